// Round 10
// baseline (115.406 us; speedup 1.0000x reference)
//
#include <hip/hip_runtime.h>
#include <cstdint>
#include <cstddef>

// Problem constants: B=2, T=2048, D=1024, H=16, HD=64, causal mask.
typedef __bf16 bf16x8 __attribute__((ext_vector_type(8)));
typedef __bf16 bf16x2 __attribute__((ext_vector_type(2)));
typedef float f32x4 __attribute__((ext_vector_type(4)));
typedef float f32x16 __attribute__((ext_vector_type(16)));
typedef unsigned int u32x4 __attribute__((ext_vector_type(4)));
#define UNROLL _Pragma("unroll")

__device__ __forceinline__ unsigned short f2bf(float f) {
  unsigned int x = __builtin_bit_cast(unsigned int, f);
  x += 0x7fffu + ((x >> 16) & 1u);   // RNE
  return (unsigned short)(x >> 16);
}
__device__ __forceinline__ float bf2f(unsigned short u) {
  return __builtin_bit_cast(float, (unsigned int)u << 16);
}
__device__ __forceinline__ unsigned int cvtpk(float a, float b) {
  bf16x2 t; t[0] = (__bf16)a; t[1] = (__bf16)b;
  return __builtin_bit_cast(unsigned int, t);
}
__device__ __forceinline__ void async16(const void* g, void* l) {
  __builtin_amdgcn_global_load_lds((void __attribute__((address_space(1)))*)g,
                                   (void __attribute__((address_space(3)))*)l,
                                   16, 0, 0);
}

// ---------------- prep: x f32 -> bf16 ----------------
__global__ void prep_x(const float* __restrict__ x, unsigned short* __restrict__ xb) {
  int i = blockIdx.x * 256 + threadIdx.x;
  const float4* p = (const float4*)(x + (size_t)i * 8);
  float4 a = p[0], b = p[1];
  ushort4 o0 = {f2bf(a.x), f2bf(a.y), f2bf(a.z), f2bf(a.w)};
  ushort4 o1 = {f2bf(b.x), f2bf(b.y), f2bf(b.z), f2bf(b.w)};
  ushort4* q = (ushort4*)(xb + (size_t)i * 8);
  q[0] = o0; q[1] = o1;
}

// ------------- prep: weights -> transposed bf16 [N][K] -------------
__global__ void prep_w(const float* __restrict__ wq, const float* __restrict__ wk,
                       const float* __restrict__ wv, const float* __restrict__ wo,
                       unsigned short* __restrict__ out) {
  __shared__ float tile[32][33];
  const float* src = blockIdx.z == 0 ? wq : blockIdx.z == 1 ? wk : blockIdx.z == 2 ? wv : wo;
  unsigned short* dst = out + (size_t)blockIdx.z * 1048576;
  int kb = blockIdx.x * 32, nb = blockIdx.y * 32;
  int c = threadIdx.x & 31, r4 = (threadIdx.x >> 5) * 4;
UNROLL
  for (int i = 0; i < 4; ++i)
    tile[r4 + i][c] = src[(size_t)(kb + r4 + i) * 1024 + nb + c];
  __syncthreads();
UNROLL
  for (int i = 0; i < 4; ++i)
    dst[(size_t)(nb + r4 + i) * 1024 + kb + c] = f2bf(tile[c][r4 + i]);
}

// ------------- prep: rope table (cos,sin) per (t, i<32) -------------
__global__ void prep_rope(float2* __restrict__ tab) {
  int idx = blockIdx.x * 256 + threadIdx.x;
  int t = idx >> 5, i = idx & 31;
  float inv = exp2f(-(float)i * (13.287712379549449f / 32.0f));
  float ang = (float)t * inv;
  tab[idx] = make_float2(cosf(ang), sinf(ang));
}

// ======== QKV GEMM: 128x128 tile, BK=32, double-buffered + counted vmcnt ========
// LDS rows are 64B -> XOR swizzle byte ^= (row&3)<<4, both-sides (rule 21):
// linear LDS dest + inverse-swizzled global source + swizzled ds_read.
__global__ __launch_bounds__(256, 3) void gemmqkv(
    const unsigned short* __restrict__ A, const unsigned short* __restrict__ Bt,
    unsigned short* __restrict__ qout, unsigned short* __restrict__ kout,
    unsigned short* __restrict__ vtout, const float2* __restrict__ rope) {
  __shared__ __align__(16) unsigned short As[2][128 * 32];  // 2 x 8KB
  __shared__ __align__(16) unsigned short Bs[2][128 * 32];  // 2 x 8KB
  const int tid = threadIdx.x;
  const int lane = tid & 63, wid = tid >> 6;
  const int wr = wid >> 1, wc = wid & 1;          // wave tile 64x64
  const int g = lane >> 4, r16 = lane & 15;
  const int m0 = blockIdx.y * 128, n0 = blockIdx.x * 128;

  f32x4 acc[4][4];
UNROLL
  for (int i = 0; i < 4; ++i)
UNROLL
    for (int j = 0; j < 4; ++j) acc[i][j] = (f32x4){0.f, 0.f, 0.f, 0.f};

  // staging: row = tid>>2 (+64 for 2nd issue), slot = tid&3 (4 x 16B per 64B row)
  const int ce = (((tid & 3) ^ ((tid >> 2) & 3)) << 3);   // inverse-swizzled k-elems
  const unsigned short* gA = A + (size_t)(m0 + (tid >> 2)) * 1024 + ce;
  const unsigned short* gB = Bt + (size_t)(n0 + (tid >> 2)) * 1024 + ce;
  const int dst0 = tid * 16;                      // bytes
  const int swz = (r16 & 3) << 4;

#define QSTG(bb, koff) { \
    async16(gA + (koff),             (char*)As[bb] + dst0); \
    async16(gA + 64 * 1024 + (koff), (char*)As[bb] + dst0 + 4096); \
    async16(gB + (koff),             (char*)Bs[bb] + dst0); \
    async16(gB + 64 * 1024 + (koff), (char*)Bs[bb] + dst0 + 4096); }

  QSTG(0, 0)
  for (int u = 0; u < 32; ++u) {
    const int bsel = u & 1;
    if (u + 1 < 32) { QSTG(bsel ^ 1, (u + 1) * 32) }
    __builtin_amdgcn_sched_barrier(0);
    if (u + 1 < 32) { asm volatile("s_waitcnt vmcnt(4)" ::: "memory"); }
    else            { asm volatile("s_waitcnt vmcnt(0)" ::: "memory"); }
    __builtin_amdgcn_s_barrier();
    __builtin_amdgcn_sched_barrier(0);
    bf16x8 af[4], bfr[4];
UNROLL
    for (int mi = 0; mi < 4; ++mi)
      af[mi] = *(const bf16x8*)((const char*)As[bsel] +
                (wr * 64 + mi * 16 + r16) * 64 + ((g * 16) ^ swz));
UNROLL
    for (int ni = 0; ni < 4; ++ni)
      bfr[ni] = *(const bf16x8*)((const char*)Bs[bsel] +
                (wc * 64 + ni * 16 + r16) * 64 + ((g * 16) ^ swz));
UNROLL
    for (int mi = 0; mi < 4; ++mi)
UNROLL
      for (int ni = 0; ni < 4; ++ni)
        acc[mi][ni] = __builtin_amdgcn_mfma_f32_16x16x32_bf16(af[mi], bfr[ni],
                                                              acc[mi][ni], 0, 0, 0);
    __builtin_amdgcn_sched_barrier(0);
    __builtin_amdgcn_s_barrier();
  }
#undef QSTG

  // ---- fused RoPE + scatter epilogue (q/k/vt) ----
  const int which = n0 >> 10;
  const int b = (m0 >= 2048) ? 1 : 0;
  const float QSCL = 0.18033688011112042f;        // 1/sqrt(64) * log2(e)
UNROLL
  for (int mi = 0; mi < 4; ++mi) {
    const int rowb = m0 + wr * 64 + mi * 16 + g * 4;
    const int trow = rowb & 2047;
UNROLL
    for (int ni = 0; ni < 4; ++ni) {
      const int n = n0 + wc * 64 + ni * 16 + r16;
      const int h = (n >> 6) & 15, e = n & 63;
      f32x4 v = acc[mi][ni];
      if (which < 2) {
        const int fi = e >> 1;
        const bool ev = (e & 1) == 0;
UNROLL
        for (int j = 0; j < 4; ++j) {
          float2 cs = rope[(trow + j) * 32 + fi];
          float p = __shfl_xor(v[j], 1);
          v[j] = ev ? (v[j] * cs.x - p * cs.y) : (v[j] * cs.x + p * cs.y);
        }
        if (which == 0) { v[0] *= QSCL; v[1] *= QSCL; v[2] *= QSCL; v[3] *= QSCL; }
      }
      if (which == 2) {
        size_t base = (((size_t)b * 16 + h) * 64 + e) * 2048 + trow;
        ushort4 pkv = {f2bf(v[0]), f2bf(v[1]), f2bf(v[2]), f2bf(v[3])};
        *(ushort4*)(vtout + base) = pkv;
      } else {
        unsigned short* dst = (which == 0) ? qout : kout;
        size_t base = (((size_t)b * 16 + h) * 2048 + trow) * 64 + e;
UNROLL
        for (int j = 0; j < 4; ++j) dst[base + (size_t)j * 64] = f2bf(v[j]);
      }
    }
  }
}

// ======== output projection: 64x64 tiles, BK=64, double-buffered + counted vmcnt ========
__global__ __launch_bounds__(256, 4) void gemm_o(
    const unsigned short* __restrict__ A, const unsigned short* __restrict__ Bt,
    float* __restrict__ out) {
  __shared__ __align__(16) unsigned short As[2][64 * 64]; // 2 x 8KB
  __shared__ __align__(16) unsigned short Bs[2][64 * 64]; // 2 x 8KB
  const int tid = threadIdx.x;
  const int lane = tid & 63, wid = tid >> 6;
  const int wm = wid >> 1, wn = wid & 1;          // wave tile 32x32
  const int g = lane >> 4, r16 = lane & 15;
  const int m0 = blockIdx.y * 64, n0 = blockIdx.x * 64;

  f32x4 acc[2][2];
UNROLL
  for (int i = 0; i < 2; ++i)
UNROLL
    for (int j = 0; j < 2; ++j) acc[i][j] = (f32x4){0.f, 0.f, 0.f, 0.f};

  const int ce = (((tid & 7) ^ ((tid >> 3) & 7)) << 3);
  const unsigned short* gA = A + (size_t)(m0 + (tid >> 3)) * 1024 + ce;
  const unsigned short* gB = Bt + (size_t)(n0 + (tid >> 3)) * 1024 + ce;
  const int dst0 = tid * 16;
  const int swz = (r16 & 7) << 4;

#define OSTG(bb, koff) { \
    async16(gA + (koff),             (char*)As[bb] + dst0); \
    async16(gA + 32 * 1024 + (koff), (char*)As[bb] + dst0 + 4096); \
    async16(gB + (koff),             (char*)Bs[bb] + dst0); \
    async16(gB + 32 * 1024 + (koff), (char*)Bs[bb] + dst0 + 4096); }

  OSTG(0, 0)
  for (int u = 0; u < 16; ++u) {
    const int bsel = u & 1;
    if (u + 1 < 16) { OSTG(bsel ^ 1, (u + 1) * 64) }
    __builtin_amdgcn_sched_barrier(0);
    if (u + 1 < 16) { asm volatile("s_waitcnt vmcnt(4)" ::: "memory"); }
    else            { asm volatile("s_waitcnt vmcnt(0)" ::: "memory"); }
    __builtin_amdgcn_s_barrier();
    __builtin_amdgcn_sched_barrier(0);
UNROLL
    for (int kk = 0; kk < 2; ++kk) {
      bf16x8 af[2], bfr[2];
UNROLL
      for (int mi = 0; mi < 2; ++mi)
        af[mi] = *(const bf16x8*)((const char*)As[bsel] +
                  (wm * 32 + mi * 16 + r16) * 128 + ((kk * 64 + g * 16) ^ swz));
UNROLL
      for (int ni = 0; ni < 2; ++ni)
        bfr[ni] = *(const bf16x8*)((const char*)Bs[bsel] +
                  (wn * 32 + ni * 16 + r16) * 128 + ((kk * 64 + g * 16) ^ swz));
UNROLL
      for (int mi = 0; mi < 2; ++mi)
UNROLL
        for (int ni = 0; ni < 2; ++ni)
          acc[mi][ni] = __builtin_amdgcn_mfma_f32_16x16x32_bf16(af[mi], bfr[ni],
                                                                acc[mi][ni], 0, 0, 0);
    }
    __builtin_amdgcn_sched_barrier(0);
    __builtin_amdgcn_s_barrier();
  }
#undef OSTG

UNROLL
  for (int mi = 0; mi < 2; ++mi) {
    const int rowb = m0 + wm * 32 + mi * 16 + g * 4;
UNROLL
    for (int ni = 0; ni < 2; ++ni) {
      const int n = n0 + wn * 32 + ni * 16 + r16;
UNROLL
      for (int j = 0; j < 4; ++j)
        out[(size_t)(rowb + j) * 1024 + n] = acc[mi][ni][j];
    }
  }
}

// ======== flash attention: scale-free softmax (P=exp2(s)), l via MFMA ========
// O/l is invariant to P-scaling, so no max subtraction at all.  l accumulated
// with mfma(P, ones) -> lacc has the same C-layout as O (per-row, per-lane).
__device__ const signed char c_qt[32]   = {15,15,10,10,15,14,14,14,13, 9, 9, 4,13,13,12,12, 8, 8,12,11,11,11, 7, 7, 3, 6, 6, 5, 5, 2, 1, 0};
__device__ const signed char c_t0[32]   = { 0,11, 0,11,22, 0,10,20, 0, 0,10, 0,10,19, 0, 9, 0, 9,18, 0, 8,16, 0, 8, 0, 0, 7, 0, 6, 0, 0, 0};
__device__ const signed char c_len[32]  = {11,11,11,11,10,10,10,10,10,10,10,10, 9, 9, 9, 9, 9, 9, 8, 8, 8, 8, 8, 8, 8, 7, 7, 6, 6, 6, 4, 2};
__device__ const signed char c_slot[32] = {24,25,10,11,26,21,22,23,18, 8, 9,-1,19,20,15,16, 6, 7,17,12,13,14, 4, 5,-1, 2, 3, 0, 1,-1,-1,-1};

__global__ __launch_bounds__(256, 4) void attn4(
    const unsigned short* __restrict__ qb, const unsigned short* __restrict__ kb,
    const unsigned short* __restrict__ vtb, unsigned short* __restrict__ attnb,
    unsigned short* __restrict__ po, float* __restrict__ ml) {
  __shared__ __align__(16) char smem[2][16384];   // [buf][K 8KB | V^T 8KB]
  const int tid = threadIdx.x;
  const int lane = tid & 63, w = tid >> 6;
  const int l31 = lane & 31, h = lane >> 5;
  const int bh = blockIdx.x;                      // XCD = bh % 8 (L2 KV locality)
  const int item = blockIdx.y;
  const int qt = c_qt[item];
  const int t0 = c_t0[item];
  const int t1 = t0 + c_len[item];
  const int slot = c_slot[item];
  const int q0w = qt * 128 + w * 32;
  const int qg = q0w + l31;
  const size_t kvbase = (size_t)bh * (2048 * 64);

  bf16x8 qf[4];
  const unsigned short* qp = qb + kvbase + (size_t)qg * 64 + h * 8;
UNROLL
  for (int kk = 0; kk < 4; ++kk) qf[kk] = *(const bf16x8*)(qp + kk * 16);

  u32x4 of; of[0] = of[1] = of[2] = of[3] = 0x3F803F80u;  // 8 x bf16(1.0)
  const bf16x8 onesf = __builtin_bit_cast(bf16x8, of);

  const int lr = lane >> 3;
  const int cb2 = ((lane & 7) ^ lr) << 3;
  const bool isK = (w < 2);
  const int c0 = isK ? w * 4 : (w - 2) * 4;
  const unsigned short* srcp[4];
  int dstoff[4];
  const size_t step = isK ? 4096 : 64;
UNROLL
  for (int s = 0; s < 4; ++s) {
    int r = (c0 + s) * 8 + lr;
    srcp[s] = isK ? (kb + kvbase + (size_t)r * 64 + cb2)
                  : (vtb + kvbase + (size_t)r * 2048 + cb2);
    dstoff[s] = (w * 4 + s) * 1024 + lane * 16;
  }

  f32x16 o0, o1, lacc;
UNROLL
  for (int r = 0; r < 16; ++r) { o0[r] = 0.f; o1[r] = 0.f; lacc[r] = 0.f; }

UNROLL
  for (int s = 0; s < 4; ++s) async16(srcp[s] + (size_t)t0 * step, &smem[0][0] + dstoff[s]);

  const int swz = (l31 & 7) << 4;
  for (int t = t0; t < t1; ++t) {
    const int kt0 = t << 6;
    // counted-vmcnt pipeline (T4): issue next tile, keep its 4 loads in flight
    if (t + 1 < t1) {
      char* db = &smem[(t + 1 - t0) & 1][0];
UNROLL
      for (int s = 0; s < 4; ++s)
        async16(srcp[s] + (size_t)(t + 1) * step, db + dstoff[s]);
      __builtin_amdgcn_sched_barrier(0);
      asm volatile("s_waitcnt vmcnt(4)" ::: "memory");
    } else {
      __builtin_amdgcn_sched_barrier(0);
      asm volatile("s_waitcnt vmcnt(0)" ::: "memory");
    }
    __builtin_amdgcn_s_barrier();
    __builtin_amdgcn_sched_barrier(0);
    if (kt0 <= q0w + 31) {
      const char* cbuf = &smem[(t - t0) & 1][0];
      f32x16 sa, sb;
UNROLL
      for (int r = 0; r < 16; ++r) { sa[r] = 0.f; sb[r] = 0.f; }
      __builtin_amdgcn_s_setprio(1);
UNROLL
      for (int kk = 0; kk < 4; ++kk) {
        bf16x8 kf = *(const bf16x8*)(cbuf + l31 * 128 + ((kk * 32 + h * 16) ^ swz));
        sa = __builtin_amdgcn_mfma_f32_32x32x16_bf16(kf, qf[kk], sa, 0, 0, 0);
      }
UNROLL
      for (int kk = 0; kk < 4; ++kk) {
        bf16x8 kf = *(const bf16x8*)(cbuf + (32 + l31) * 128 + ((kk * 32 + h * 16) ^ swz));
        sb = __builtin_amdgcn_mfma_f32_32x32x16_bf16(kf, qf[kk], sb, 0, 0, 0);
      }
      __builtin_amdgcn_s_setprio(0);
      if (kt0 + 63 > q0w) {                       // causal mask (diagonal only)
UNROLL
        for (int r = 0; r < 16; ++r) {
          int koff = (r & 3) + 8 * (r >> 2) + 4 * h;
          if (kt0 + koff > qg) sa[r] = -3e38f;
          if (kt0 + 32 + koff > qg) sb[r] = -3e38f;
        }
      }
      // ---- P = exp2(s) (scale-free; masked -> exp2(-3e38) = 0) ----
UNROLL
      for (int r = 0; r < 16; ++r) {
        sa[r] = exp2f(sa[r]);
        sb[r] = exp2f(sb[r]);
      }
      // ---- P -> bf16; cross-half exchange via v_permlane32_swap ----
      unsigned int lo[8], hi[8];
UNROLL
      for (int b8 = 0; b8 < 4; ++b8) {
        lo[b8]     = cvtpk(sa[4 * b8], sa[4 * b8 + 1]);
        hi[b8]     = cvtpk(sa[4 * b8 + 2], sa[4 * b8 + 3]);
        lo[4 + b8] = cvtpk(sb[4 * b8], sb[4 * b8 + 1]);
        hi[4 + b8] = cvtpk(sb[4 * b8 + 2], sb[4 * b8 + 3]);
      }
      bf16x8 pa[4];
UNROLL
      for (int j = 0; j < 4; ++j) {
        const int bb = (j >> 1) * 4 + (j & 1) * 2;
        unsigned int a0 = lo[bb], b0 = lo[bb + 1];
        unsigned int a1 = hi[bb], b1 = hi[bb + 1];
        asm volatile("v_permlane32_swap_b32 %0, %1" : "+v"(a0), "+v"(b0));
        asm volatile("v_permlane32_swap_b32 %0, %1" : "+v"(a1), "+v"(b1));
        u32x4 f;
        f[0] = a0; f[1] = a1; f[2] = b0; f[3] = b1;
        pa[j] = __builtin_bit_cast(bf16x8, f);
      }
      // ---- O += P.V ; l += P.1 (same A-fragments, C-layout matches O) ----
      __builtin_amdgcn_s_setprio(1);
UNROLL
      for (int j = 0; j < 4; ++j) {
        bf16x8 v0 = *(const bf16x8*)(cbuf + 8192 + l31 * 128 + ((j * 32 + h * 16) ^ swz));
        bf16x8 v1 = *(const bf16x8*)(cbuf + 8192 + (32 + l31) * 128 + ((j * 32 + h * 16) ^ swz));
        o0 = __builtin_amdgcn_mfma_f32_32x32x16_bf16(pa[j], v0, o0, 0, 0, 0);
        o1 = __builtin_amdgcn_mfma_f32_32x32x16_bf16(pa[j], v1, o1, 0, 0, 0);
        lacc = __builtin_amdgcn_mfma_f32_32x32x16_bf16(pa[j], onesf, lacc, 0, 0, 0);
      }
      __builtin_amdgcn_s_setprio(0);
    }
    __builtin_amdgcn_sched_barrier(0);
    __builtin_amdgcn_s_barrier();
  }

  // ---- epilogue: lacc[r] is l for this lane's rows (all cols identical) ----
  if (slot < 0) {
    const int b = bh >> 4, hh = bh & 15;
UNROLL
    for (int r = 0; r < 16; ++r) {
      const int qg2 = q0w + (r & 3) + 8 * (r >> 2) + 4 * h;
      const size_t base = (((size_t)b * 2048 + qg2) * 16 + hh) * 64 + l31;
      const float iv = 1.0f / lacc[r];
      attnb[base]      = f2bf(o0[r] * iv);
      attnb[base + 32] = f2bf(o1[r] * iv);
    }
  } else {
    const int p = bh * 27 + slot;
    if (l31 == 0) {
UNROLL
      for (int r = 0; r < 16; ++r)
        ml[p * 128 + w * 32 + (r & 3) + 8 * (r >> 2) + 4 * h] = lacc[r];
    }
    unsigned short* pb = po + (size_t)p * 8192;
UNROLL
    for (int r = 0; r < 16; ++r) {
      const int rl = w * 32 + (r & 3) + 8 * (r >> 2) + 4 * h;
      const float iv = 1.0f / lacc[r];
      pb[rl * 64 + l31]      = f2bf(o0[r] * iv);
      pb[rl * 64 + l31 + 32] = f2bf(o1[r] * iv);
    }
  }
}

// ---------------- combine partials: l-weighted average (no exp) ----------------
__global__ void attn_combine(const unsigned short* __restrict__ po,
                             const float* __restrict__ ml,
                             unsigned short* __restrict__ attnb) {
  const int idx = blockIdx.x * 256 + threadIdx.x;   // 32*11*128*4 = 180224
  const int cg = idx & 3;                           // 16 cols each
  const int row = (idx >> 2) & 127;
  const int t2 = idx >> 9;                          // bh*11 + qi
  const int qi = t2 % 11;
  const int bh = t2 / 11;
  const int qt = qi + 5;
  const int cnt = (qt < 11) ? 2 : 3;
  const int base = (qt < 11) ? (qt - 5) * 2 : 12 + (qt - 11) * 3;
  const int slotg = bh * 27 + base;
  float acc[16];
UNROLL
  for (int i = 0; i < 16; ++i) acc[i] = 0.f;
  float wsum = 0.f;
  for (int i = 0; i < cnt; ++i) {
    const float l = ml[(slotg + i) * 128 + row];
    wsum += l;
    const ushort4* p = (const ushort4*)(po + (size_t)(slotg + i) * 8192 + row * 64 + cg * 16);
UNROLL
    for (int v = 0; v < 4; ++v) {
      ushort4 u = p[v];
      acc[v * 4 + 0] += l * bf2f(u.x);
      acc[v * 4 + 1] += l * bf2f(u.y);
      acc[v * 4 + 2] += l * bf2f(u.z);
      acc[v * 4 + 3] += l * bf2f(u.w);
    }
  }
  const float inv = 1.0f / wsum;
  const int b = bh >> 4, hh = bh & 15;
  const int q = qt * 128 + row;
  ushort4* out = (ushort4*)(attnb + (((size_t)b * 2048 + q) * 16 + hh) * 64 + cg * 16);
UNROLL
  for (int v = 0; v < 4; ++v) {
    ushort4 o;
    o.x = f2bf(acc[v * 4 + 0] * inv);
    o.y = f2bf(acc[v * 4 + 1] * inv);
    o.z = f2bf(acc[v * 4 + 2] * inv);
    o.w = f2bf(acc[v * 4 + 3] * inv);
    out[v] = o;
  }
}

extern "C" void kernel_launch(void* const* d_in, const int* in_sizes, int n_in,
                              void* d_out, int out_size, void* d_ws, size_t ws_size,
                              hipStream_t stream) {
  (void)in_sizes; (void)n_in; (void)out_size; (void)ws_size;
  const float* x = (const float*)d_in[0];
  const float* wq = (const float*)d_in[2];
  const float* wk = (const float*)d_in[3];
  const float* wv = (const float*)d_in[4];
  const float* wo = (const float*)d_in[5];

  unsigned short* xb = (unsigned short*)d_ws;           // 4M elems (8MB)
  unsigned short* wT = xb + 4 * 1024 * 1024;            // 4M
  float2* rope = (float2*)(wT + 4 * 1024 * 1024);       // 64K float2 (512KB)
  unsigned short* qb = (unsigned short*)(rope + 65536); // 4M
  unsigned short* kbuf = qb + 4 * 1024 * 1024;          // 4M
  unsigned short* vtb = kbuf + 4 * 1024 * 1024;         // 4M
  unsigned short* attnb = vtb + 4 * 1024 * 1024;        // 4M

  unsigned short* po = xb;          // partials alias xb+weights (dead after gemmqkv)
  float* mlb = (float*)rope;        // l-table aliases rope (dead after gemmqkv)

  prep_x<<<dim3(2048), dim3(256), 0, stream>>>(x, xb);
  prep_w<<<dim3(32, 32, 4), dim3(256), 0, stream>>>(wq, wk, wv, wo, wT);
  prep_rope<<<dim3(256), dim3(256), 0, stream>>>(rope);
  gemmqkv<<<dim3(24, 32), dim3(256), 0, stream>>>(xb, wT, qb, kbuf, vtb, rope);
  attn4<<<dim3(32, 32), dim3(256), 0, stream>>>(qb, kbuf, vtb, attnb, po, mlb);
  attn_combine<<<dim3(704), dim3(256), 0, stream>>>(po, mlb, attnb);
  gemm_o<<<dim3(16, 64), dim3(256), 0, stream>>>(attnb, wT + 3 * 1024 * 1024,
                                                 (float*)d_out);
}

// Round 11
// 111.648 us; speedup vs baseline: 1.0337x; 1.0337x over previous
//
#include <hip/hip_runtime.h>
#include <cstdint>
#include <cstddef>

// Problem constants: B=2, T=2048, D=1024, H=16, HD=64, causal mask.
typedef __bf16 bf16x8 __attribute__((ext_vector_type(8)));
typedef __bf16 bf16x2 __attribute__((ext_vector_type(2)));
typedef float f32x4 __attribute__((ext_vector_type(4)));
typedef float f32x16 __attribute__((ext_vector_type(16)));
typedef unsigned int u32x4 __attribute__((ext_vector_type(4)));
#define UNROLL _Pragma("unroll")

__device__ __forceinline__ unsigned short f2bf(float f) {
  unsigned int x = __builtin_bit_cast(unsigned int, f);
  x += 0x7fffu + ((x >> 16) & 1u);   // RNE
  return (unsigned short)(x >> 16);
}
__device__ __forceinline__ float bf2f(unsigned short u) {
  return __builtin_bit_cast(float, (unsigned int)u << 16);
}
__device__ __forceinline__ unsigned int cvtpk(float a, float b) {
  bf16x2 t; t[0] = (__bf16)a; t[1] = (__bf16)b;
  return __builtin_bit_cast(unsigned int, t);
}
__device__ __forceinline__ void async16(const void* g, void* l) {
  __builtin_amdgcn_global_load_lds((void __attribute__((address_space(1)))*)g,
                                   (void __attribute__((address_space(3)))*)l,
                                   16, 0, 0);
}

// ---------------- prep: x f32 -> bf16 ----------------
__global__ void prep_x(const float* __restrict__ x, unsigned short* __restrict__ xb) {
  int i = blockIdx.x * 256 + threadIdx.x;
  const float4* p = (const float4*)(x + (size_t)i * 8);
  float4 a = p[0], b = p[1];
  ushort4 o0 = {f2bf(a.x), f2bf(a.y), f2bf(a.z), f2bf(a.w)};
  ushort4 o1 = {f2bf(b.x), f2bf(b.y), f2bf(b.z), f2bf(b.w)};
  ushort4* q = (ushort4*)(xb + (size_t)i * 8);
  q[0] = o0; q[1] = o1;
}

// ------------- prep: weights -> transposed bf16 [N][K] -------------
__global__ void prep_w(const float* __restrict__ wq, const float* __restrict__ wk,
                       const float* __restrict__ wv, const float* __restrict__ wo,
                       unsigned short* __restrict__ out) {
  __shared__ float tile[32][33];
  const float* src = blockIdx.z == 0 ? wq : blockIdx.z == 1 ? wk : blockIdx.z == 2 ? wv : wo;
  unsigned short* dst = out + (size_t)blockIdx.z * 1048576;
  int kb = blockIdx.x * 32, nb = blockIdx.y * 32;
  int c = threadIdx.x & 31, r4 = (threadIdx.x >> 5) * 4;
UNROLL
  for (int i = 0; i < 4; ++i)
    tile[r4 + i][c] = src[(size_t)(kb + r4 + i) * 1024 + nb + c];
  __syncthreads();
UNROLL
  for (int i = 0; i < 4; ++i)
    dst[(size_t)(nb + r4 + i) * 1024 + kb + c] = f2bf(tile[c][r4 + i]);
}

// ------------- prep: rope table (cos,sin) per (t, i<32) -------------
__global__ void prep_rope(float2* __restrict__ tab) {
  int idx = blockIdx.x * 256 + threadIdx.x;
  int t = idx >> 5, i = idx & 31;
  float inv = exp2f(-(float)i * (13.287712379549449f / 32.0f));
  float ang = (float)t * inv;
  tab[idx] = make_float2(cosf(ang), sinf(ang));
}

// ======== QKV GEMM: 128x128 tile, BK=64 (16 K-steps), m97 shell, swizzled LDS ========
// 128B rows -> XOR swizzle byte ^= (row&7)<<4 (proven 0-conflict), both-sides:
// linear LDS dest + inverse-swizzled global source + swizzled ds_read.
__global__ __launch_bounds__(256, 3) void gemmqkv(
    const unsigned short* __restrict__ A, const unsigned short* __restrict__ Bt,
    unsigned short* __restrict__ qout, unsigned short* __restrict__ kout,
    unsigned short* __restrict__ vtout, const float2* __restrict__ rope) {
  __shared__ __align__(16) unsigned short As[128 * 64];   // 16KB
  __shared__ __align__(16) unsigned short Bs[128 * 64];   // 16KB
  const int tid = threadIdx.x;
  const int lane = tid & 63, wid = tid >> 6;
  const int wr = wid >> 1, wc = wid & 1;          // wave tile 64x64
  const int g = lane >> 4, r16 = lane & 15;
  const int m0 = blockIdx.y * 128, n0 = blockIdx.x * 128;

  f32x4 acc[4][4];
UNROLL
  for (int i = 0; i < 4; ++i)
UNROLL
    for (int j = 0; j < 4; ++j) acc[i][j] = (f32x4){0.f, 0.f, 0.f, 0.f};

  const int ce = (((tid & 7) ^ ((tid >> 3) & 7)) << 3);
  const unsigned short* gA = A + (size_t)(m0 + (tid >> 3)) * 1024 + ce;
  const unsigned short* gB = Bt + (size_t)(n0 + (tid >> 3)) * 1024 + ce;
  char* lA = (char*)As + tid * 16;
  char* lB = (char*)Bs + tid * 16;

  const int swz = (r16 & 7) << 4;

  for (int u = 0; u < 16; ++u) {
    const int k0 = u * 64;
UNROLL
    for (int s = 0; s < 4; ++s) {
      async16(gA + (size_t)s * 32 * 1024 + k0, lA + s * 4096);
      async16(gB + (size_t)s * 32 * 1024 + k0, lB + s * 4096);
    }
    __syncthreads();
UNROLL
    for (int kk = 0; kk < 2; ++kk) {
      bf16x8 af[4], bfr[4];
UNROLL
      for (int mi = 0; mi < 4; ++mi)
        af[mi] = *(const bf16x8*)((const char*)As +
                  (wr * 64 + mi * 16 + r16) * 128 + ((kk * 64 + g * 16) ^ swz));
UNROLL
      for (int ni = 0; ni < 4; ++ni)
        bfr[ni] = *(const bf16x8*)((const char*)Bs +
                  (wc * 64 + ni * 16 + r16) * 128 + ((kk * 64 + g * 16) ^ swz));
UNROLL
      for (int mi = 0; mi < 4; ++mi)
UNROLL
        for (int ni = 0; ni < 4; ++ni)
          acc[mi][ni] = __builtin_amdgcn_mfma_f32_16x16x32_bf16(af[mi], bfr[ni],
                                                                acc[mi][ni], 0, 0, 0);
    }
    __syncthreads();
  }

  // ---- fused RoPE + scatter epilogue (q/k/vt) ----
  const int which = n0 >> 10;
  const int b = (m0 >= 2048) ? 1 : 0;
  const float QSCL = 0.18033688011112042f;        // 1/sqrt(64) * log2(e)
UNROLL
  for (int mi = 0; mi < 4; ++mi) {
    const int rowb = m0 + wr * 64 + mi * 16 + g * 4;
    const int trow = rowb & 2047;
UNROLL
    for (int ni = 0; ni < 4; ++ni) {
      const int n = n0 + wc * 64 + ni * 16 + r16;
      const int h = (n >> 6) & 15, e = n & 63;
      f32x4 v = acc[mi][ni];
      if (which < 2) {
        const int fi = e >> 1;
        const bool ev = (e & 1) == 0;
UNROLL
        for (int j = 0; j < 4; ++j) {
          float2 cs = rope[(trow + j) * 32 + fi];
          float p = __shfl_xor(v[j], 1);
          v[j] = ev ? (v[j] * cs.x - p * cs.y) : (v[j] * cs.x + p * cs.y);
        }
        if (which == 0) { v[0] *= QSCL; v[1] *= QSCL; v[2] *= QSCL; v[3] *= QSCL; }
      }
      if (which == 2) {
        size_t base = (((size_t)b * 16 + h) * 64 + e) * 2048 + trow;
        ushort4 pkv = {f2bf(v[0]), f2bf(v[1]), f2bf(v[2]), f2bf(v[3])};
        *(ushort4*)(vtout + base) = pkv;
      } else {
        unsigned short* dst = (which == 0) ? qout : kout;
        size_t base = (((size_t)b * 16 + h) * 2048 + trow) * 64 + e;
UNROLL
        for (int j = 0; j < 4; ++j) dst[base + (size_t)j * 64] = f2bf(v[j]);
      }
    }
  }
}

// ======== output projection: 64x64 tiles, BK=64, double-buffered + counted vmcnt ========
__global__ __launch_bounds__(256, 4) void gemm_o(
    const unsigned short* __restrict__ A, const unsigned short* __restrict__ Bt,
    float* __restrict__ out) {
  __shared__ __align__(16) unsigned short As[2][64 * 64]; // 2 x 8KB
  __shared__ __align__(16) unsigned short Bs[2][64 * 64]; // 2 x 8KB
  const int tid = threadIdx.x;
  const int lane = tid & 63, wid = tid >> 6;
  const int wm = wid >> 1, wn = wid & 1;          // wave tile 32x32
  const int g = lane >> 4, r16 = lane & 15;
  const int m0 = blockIdx.y * 64, n0 = blockIdx.x * 64;

  f32x4 acc[2][2];
UNROLL
  for (int i = 0; i < 2; ++i)
UNROLL
    for (int j = 0; j < 2; ++j) acc[i][j] = (f32x4){0.f, 0.f, 0.f, 0.f};

  const int ce = (((tid & 7) ^ ((tid >> 3) & 7)) << 3);
  const unsigned short* gA = A + (size_t)(m0 + (tid >> 3)) * 1024 + ce;
  const unsigned short* gB = Bt + (size_t)(n0 + (tid >> 3)) * 1024 + ce;
  const int dst0 = tid * 16;
  const int swz = (r16 & 7) << 4;

#define OSTG(bb, koff) { \
    async16(gA + (koff),             (char*)As[bb] + dst0); \
    async16(gA + 32 * 1024 + (koff), (char*)As[bb] + dst0 + 4096); \
    async16(gB + (koff),             (char*)Bs[bb] + dst0); \
    async16(gB + 32 * 1024 + (koff), (char*)Bs[bb] + dst0 + 4096); }

  OSTG(0, 0)
  for (int u = 0; u < 16; ++u) {
    const int bsel = u & 1;
    if (u + 1 < 16) { OSTG(bsel ^ 1, (u + 1) * 64) }
    __builtin_amdgcn_sched_barrier(0);
    if (u + 1 < 16) { asm volatile("s_waitcnt vmcnt(4)" ::: "memory"); }
    else            { asm volatile("s_waitcnt vmcnt(0)" ::: "memory"); }
    __builtin_amdgcn_s_barrier();
    __builtin_amdgcn_sched_barrier(0);
UNROLL
    for (int kk = 0; kk < 2; ++kk) {
      bf16x8 af[2], bfr[2];
UNROLL
      for (int mi = 0; mi < 2; ++mi)
        af[mi] = *(const bf16x8*)((const char*)As[bsel] +
                  (wm * 32 + mi * 16 + r16) * 128 + ((kk * 64 + g * 16) ^ swz));
UNROLL
      for (int ni = 0; ni < 2; ++ni)
        bfr[ni] = *(const bf16x8*)((const char*)Bs[bsel] +
                  (wn * 32 + ni * 16 + r16) * 128 + ((kk * 64 + g * 16) ^ swz));
UNROLL
      for (int mi = 0; mi < 2; ++mi)
UNROLL
        for (int ni = 0; ni < 2; ++ni)
          acc[mi][ni] = __builtin_amdgcn_mfma_f32_16x16x32_bf16(af[mi], bfr[ni],
                                                                acc[mi][ni], 0, 0, 0);
    }
    __builtin_amdgcn_sched_barrier(0);
    __builtin_amdgcn_s_barrier();
  }
#undef OSTG

UNROLL
  for (int mi = 0; mi < 2; ++mi) {
    const int rowb = m0 + wm * 32 + mi * 16 + g * 4;
UNROLL
    for (int ni = 0; ni < 2; ++ni) {
      const int n = n0 + wn * 32 + ni * 16 + r16;
UNROLL
      for (int j = 0; j < 4; ++j)
        out[(size_t)(rowb + j) * 1024 + n] = acc[mi][ni][j];
    }
  }
}

// ======== flash attention: scale-free softmax (P=exp2(s)), l via MFMA ========
__device__ const signed char c_qt[32]   = {15,15,10,10,15,14,14,14,13, 9, 9, 4,13,13,12,12, 8, 8,12,11,11,11, 7, 7, 3, 6, 6, 5, 5, 2, 1, 0};
__device__ const signed char c_t0[32]   = { 0,11, 0,11,22, 0,10,20, 0, 0,10, 0,10,19, 0, 9, 0, 9,18, 0, 8,16, 0, 8, 0, 0, 7, 0, 6, 0, 0, 0};
__device__ const signed char c_len[32]  = {11,11,11,11,10,10,10,10,10,10,10,10, 9, 9, 9, 9, 9, 9, 8, 8, 8, 8, 8, 8, 8, 7, 7, 6, 6, 6, 4, 2};
__device__ const signed char c_slot[32] = {24,25,10,11,26,21,22,23,18, 8, 9,-1,19,20,15,16, 6, 7,17,12,13,14, 4, 5,-1, 2, 3, 0, 1,-1,-1,-1};

__global__ __launch_bounds__(256, 4) void attn4(
    const unsigned short* __restrict__ qb, const unsigned short* __restrict__ kb,
    const unsigned short* __restrict__ vtb, unsigned short* __restrict__ attnb,
    unsigned short* __restrict__ po, float* __restrict__ ml) {
  __shared__ __align__(16) char smem[2][16384];   // [buf][K 8KB | V^T 8KB]
  const int tid = threadIdx.x;
  const int lane = tid & 63, w = tid >> 6;
  const int l31 = lane & 31, h = lane >> 5;
  const int bh = blockIdx.x;                      // XCD = bh % 8 (L2 KV locality)
  const int item = blockIdx.y;
  const int qt = c_qt[item];
  const int t0 = c_t0[item];
  const int t1 = t0 + c_len[item];
  const int slot = c_slot[item];
  const int q0w = qt * 128 + w * 32;
  const int qg = q0w + l31;
  const size_t kvbase = (size_t)bh * (2048 * 64);

  bf16x8 qf[4];
  const unsigned short* qp = qb + kvbase + (size_t)qg * 64 + h * 8;
UNROLL
  for (int kk = 0; kk < 4; ++kk) qf[kk] = *(const bf16x8*)(qp + kk * 16);

  u32x4 of; of[0] = of[1] = of[2] = of[3] = 0x3F803F80u;  // 8 x bf16(1.0)
  const bf16x8 onesf = __builtin_bit_cast(bf16x8, of);

  const int lr = lane >> 3;
  const int cb2 = ((lane & 7) ^ lr) << 3;
  const bool isK = (w < 2);
  const int c0 = isK ? w * 4 : (w - 2) * 4;
  const unsigned short* srcp[4];
  int dstoff[4];
  const size_t step = isK ? 4096 : 64;
UNROLL
  for (int s = 0; s < 4; ++s) {
    int r = (c0 + s) * 8 + lr;
    srcp[s] = isK ? (kb + kvbase + (size_t)r * 64 + cb2)
                  : (vtb + kvbase + (size_t)r * 2048 + cb2);
    dstoff[s] = (w * 4 + s) * 1024 + lane * 16;
  }

  f32x16 o0, o1, lacc;
UNROLL
  for (int r = 0; r < 16; ++r) { o0[r] = 0.f; o1[r] = 0.f; lacc[r] = 0.f; }

UNROLL
  for (int s = 0; s < 4; ++s) async16(srcp[s] + (size_t)t0 * step, &smem[0][0] + dstoff[s]);

  const int swz = (l31 & 7) << 4;
  for (int t = t0; t < t1; ++t) {
    const int kt0 = t << 6;
    if (t + 1 < t1) {
      char* db = &smem[(t + 1 - t0) & 1][0];
UNROLL
      for (int s = 0; s < 4; ++s)
        async16(srcp[s] + (size_t)(t + 1) * step, db + dstoff[s]);
      __builtin_amdgcn_sched_barrier(0);
      asm volatile("s_waitcnt vmcnt(4)" ::: "memory");
    } else {
      __builtin_amdgcn_sched_barrier(0);
      asm volatile("s_waitcnt vmcnt(0)" ::: "memory");
    }
    __builtin_amdgcn_s_barrier();
    __builtin_amdgcn_sched_barrier(0);
    if (kt0 <= q0w + 31) {
      const char* cbuf = &smem[(t - t0) & 1][0];
      f32x16 sa, sb;
UNROLL
      for (int r = 0; r < 16; ++r) { sa[r] = 0.f; sb[r] = 0.f; }
      __builtin_amdgcn_s_setprio(1);
UNROLL
      for (int kk = 0; kk < 4; ++kk) {
        bf16x8 kf = *(const bf16x8*)(cbuf + l31 * 128 + ((kk * 32 + h * 16) ^ swz));
        sa = __builtin_amdgcn_mfma_f32_32x32x16_bf16(kf, qf[kk], sa, 0, 0, 0);
      }
UNROLL
      for (int kk = 0; kk < 4; ++kk) {
        bf16x8 kf = *(const bf16x8*)(cbuf + (32 + l31) * 128 + ((kk * 32 + h * 16) ^ swz));
        sb = __builtin_amdgcn_mfma_f32_32x32x16_bf16(kf, qf[kk], sb, 0, 0, 0);
      }
      __builtin_amdgcn_s_setprio(0);
      if (kt0 + 63 > q0w) {                       // causal mask (diagonal only)
UNROLL
        for (int r = 0; r < 16; ++r) {
          int koff = (r & 3) + 8 * (r >> 2) + 4 * h;
          if (kt0 + koff > qg) sa[r] = -3e38f;
          if (kt0 + 32 + koff > qg) sb[r] = -3e38f;
        }
      }
UNROLL
      for (int r = 0; r < 16; ++r) {
        sa[r] = exp2f(sa[r]);
        sb[r] = exp2f(sb[r]);
      }
      unsigned int lo[8], hi[8];
UNROLL
      for (int b8 = 0; b8 < 4; ++b8) {
        lo[b8]     = cvtpk(sa[4 * b8], sa[4 * b8 + 1]);
        hi[b8]     = cvtpk(sa[4 * b8 + 2], sa[4 * b8 + 3]);
        lo[4 + b8] = cvtpk(sb[4 * b8], sb[4 * b8 + 1]);
        hi[4 + b8] = cvtpk(sb[4 * b8 + 2], sb[4 * b8 + 3]);
      }
      bf16x8 pa[4];
UNROLL
      for (int j = 0; j < 4; ++j) {
        const int bb = (j >> 1) * 4 + (j & 1) * 2;
        unsigned int a0 = lo[bb], b0 = lo[bb + 1];
        unsigned int a1 = hi[bb], b1 = hi[bb + 1];
        asm volatile("v_permlane32_swap_b32 %0, %1" : "+v"(a0), "+v"(b0));
        asm volatile("v_permlane32_swap_b32 %0, %1" : "+v"(a1), "+v"(b1));
        u32x4 f;
        f[0] = a0; f[1] = a1; f[2] = b0; f[3] = b1;
        pa[j] = __builtin_bit_cast(bf16x8, f);
      }
      __builtin_amdgcn_s_setprio(1);
UNROLL
      for (int j = 0; j < 4; ++j) {
        bf16x8 v0 = *(const bf16x8*)(cbuf + 8192 + l31 * 128 + ((j * 32 + h * 16) ^ swz));
        bf16x8 v1 = *(const bf16x8*)(cbuf + 8192 + (32 + l31) * 128 + ((j * 32 + h * 16) ^ swz));
        o0 = __builtin_amdgcn_mfma_f32_32x32x16_bf16(pa[j], v0, o0, 0, 0, 0);
        o1 = __builtin_amdgcn_mfma_f32_32x32x16_bf16(pa[j], v1, o1, 0, 0, 0);
        lacc = __builtin_amdgcn_mfma_f32_32x32x16_bf16(pa[j], onesf, lacc, 0, 0, 0);
      }
      __builtin_amdgcn_s_setprio(0);
    }
    __builtin_amdgcn_sched_barrier(0);
    __builtin_amdgcn_s_barrier();
  }

  if (slot < 0) {
    const int b = bh >> 4, hh = bh & 15;
UNROLL
    for (int r = 0; r < 16; ++r) {
      const int qg2 = q0w + (r & 3) + 8 * (r >> 2) + 4 * h;
      const size_t base = (((size_t)b * 2048 + qg2) * 16 + hh) * 64 + l31;
      const float iv = 1.0f / lacc[r];
      attnb[base]      = f2bf(o0[r] * iv);
      attnb[base + 32] = f2bf(o1[r] * iv);
    }
  } else {
    const int p = bh * 27 + slot;
    if (l31 == 0) {
UNROLL
      for (int r = 0; r < 16; ++r)
        ml[p * 128 + w * 32 + (r & 3) + 8 * (r >> 2) + 4 * h] = lacc[r];
    }
    unsigned short* pb = po + (size_t)p * 8192;
UNROLL
    for (int r = 0; r < 16; ++r) {
      const int rl = w * 32 + (r & 3) + 8 * (r >> 2) + 4 * h;
      const float iv = 1.0f / lacc[r];
      pb[rl * 64 + l31]      = f2bf(o0[r] * iv);
      pb[rl * 64 + l31 + 32] = f2bf(o1[r] * iv);
    }
  }
}

// ---------------- combine partials: l-weighted average (no exp) ----------------
__global__ void attn_combine(const unsigned short* __restrict__ po,
                             const float* __restrict__ ml,
                             unsigned short* __restrict__ attnb) {
  const int idx = blockIdx.x * 256 + threadIdx.x;   // 32*11*128*4 = 180224
  const int cg = idx & 3;                           // 16 cols each
  const int row = (idx >> 2) & 127;
  const int t2 = idx >> 9;                          // bh*11 + qi
  const int qi = t2 % 11;
  const int bh = t2 / 11;
  const int qt = qi + 5;
  const int cnt = (qt < 11) ? 2 : 3;
  const int base = (qt < 11) ? (qt - 5) * 2 : 12 + (qt - 11) * 3;
  const int slotg = bh * 27 + base;
  float acc[16];
UNROLL
  for (int i = 0; i < 16; ++i) acc[i] = 0.f;
  float wsum = 0.f;
  for (int i = 0; i < cnt; ++i) {
    const float l = ml[(slotg + i) * 128 + row];
    wsum += l;
    const ushort4* p = (const ushort4*)(po + (size_t)(slotg + i) * 8192 + row * 64 + cg * 16);
UNROLL
    for (int v = 0; v < 4; ++v) {
      ushort4 u = p[v];
      acc[v * 4 + 0] += l * bf2f(u.x);
      acc[v * 4 + 1] += l * bf2f(u.y);
      acc[v * 4 + 2] += l * bf2f(u.z);
      acc[v * 4 + 3] += l * bf2f(u.w);
    }
  }
  const float inv = 1.0f / wsum;
  const int b = bh >> 4, hh = bh & 15;
  const int q = qt * 128 + row;
  ushort4* out = (ushort4*)(attnb + (((size_t)b * 2048 + q) * 16 + hh) * 64 + cg * 16);
UNROLL
  for (int v = 0; v < 4; ++v) {
    ushort4 o;
    o.x = f2bf(acc[v * 4 + 0] * inv);
    o.y = f2bf(acc[v * 4 + 1] * inv);
    o.z = f2bf(acc[v * 4 + 2] * inv);
    o.w = f2bf(acc[v * 4 + 3] * inv);
    out[v] = o;
  }
}

extern "C" void kernel_launch(void* const* d_in, const int* in_sizes, int n_in,
                              void* d_out, int out_size, void* d_ws, size_t ws_size,
                              hipStream_t stream) {
  (void)in_sizes; (void)n_in; (void)out_size; (void)ws_size;
  const float* x = (const float*)d_in[0];
  const float* wq = (const float*)d_in[2];
  const float* wk = (const float*)d_in[3];
  const float* wv = (const float*)d_in[4];
  const float* wo = (const float*)d_in[5];

  unsigned short* xb = (unsigned short*)d_ws;           // 4M elems (8MB)
  unsigned short* wT = xb + 4 * 1024 * 1024;            // 4M
  float2* rope = (float2*)(wT + 4 * 1024 * 1024);       // 64K float2 (512KB)
  unsigned short* qb = (unsigned short*)(rope + 65536); // 4M
  unsigned short* kbuf = qb + 4 * 1024 * 1024;          // 4M
  unsigned short* vtb = kbuf + 4 * 1024 * 1024;         // 4M
  unsigned short* attnb = vtb + 4 * 1024 * 1024;        // 4M

  unsigned short* po = xb;          // partials alias xb+weights (dead after gemmqkv)
  float* mlb = (float*)rope;        // l-table aliases rope (dead after gemmqkv)

  prep_x<<<dim3(2048), dim3(256), 0, stream>>>(x, xb);
  prep_w<<<dim3(32, 32, 4), dim3(256), 0, stream>>>(wq, wk, wv, wo, wT);
  prep_rope<<<dim3(256), dim3(256), 0, stream>>>(rope);
  gemmqkv<<<dim3(24, 32), dim3(256), 0, stream>>>(xb, wT, qb, kbuf, vtb, rope);
  attn4<<<dim3(32, 32), dim3(256), 0, stream>>>(qb, kbuf, vtb, attnb, po, mlb);
  attn_combine<<<dim3(704), dim3(256), 0, stream>>>(po, mlb, attnb);
  gemm_o<<<dim3(16, 64), dim3(256), 0, stream>>>(attnb, wT + 3 * 1024 * 1024,
                                                 (float*)d_out);
}

// Round 12
// 107.625 us; speedup vs baseline: 1.0723x; 1.0374x over previous
//
#include <hip/hip_runtime.h>
#include <cstdint>
#include <cstddef>

// Problem constants: B=2, T=2048, D=1024, H=16, HD=64, causal mask.
typedef __bf16 bf16x8 __attribute__((ext_vector_type(8)));
typedef __bf16 bf16x2 __attribute__((ext_vector_type(2)));
typedef float f32x4 __attribute__((ext_vector_type(4)));
typedef float f32x16 __attribute__((ext_vector_type(16)));
typedef unsigned int u32x4 __attribute__((ext_vector_type(4)));
#define UNROLL _Pragma("unroll")

__device__ __forceinline__ unsigned short f2bf(float f) {
  unsigned int x = __builtin_bit_cast(unsigned int, f);
  x += 0x7fffu + ((x >> 16) & 1u);   // RNE
  return (unsigned short)(x >> 16);
}
__device__ __forceinline__ float bf2f(unsigned short u) {
  return __builtin_bit_cast(float, (unsigned int)u << 16);
}
__device__ __forceinline__ unsigned int cvtpk(float a, float b) {
  bf16x2 t; t[0] = (__bf16)a; t[1] = (__bf16)b;
  return __builtin_bit_cast(unsigned int, t);
}
__device__ __forceinline__ void async16(const void* g, void* l) {
  __builtin_amdgcn_global_load_lds((void __attribute__((address_space(1)))*)g,
                                   (void __attribute__((address_space(3)))*)l,
                                   16, 0, 0);
}

// ======== merged prep: x->bf16 | weights->transposed bf16 | rope table ========
__global__ void prep_all(const float* __restrict__ x,
                         const float* __restrict__ wq, const float* __restrict__ wk,
                         const float* __restrict__ wv, const float* __restrict__ wo,
                         unsigned short* __restrict__ xb,
                         unsigned short* __restrict__ wT,
                         float2* __restrict__ ropetab) {
  __shared__ float tile[32][33];
  const int bx = blockIdx.x, tid = threadIdx.x;
  if (bx < 2048) {
    // ---- x f32 -> bf16 (8 elems/thread) ----
    int i = bx * 256 + tid;
    const float4* p = (const float4*)(x + (size_t)i * 8);
    float4 a = p[0], b = p[1];
    ushort4 o0 = {f2bf(a.x), f2bf(a.y), f2bf(a.z), f2bf(a.w)};
    ushort4 o1 = {f2bf(b.x), f2bf(b.y), f2bf(b.z), f2bf(b.w)};
    ushort4* q = (ushort4*)(xb + (size_t)i * 8);
    q[0] = o0; q[1] = o1;
  } else if (bx < 6144) {
    // ---- weights -> transposed bf16 [N][K] ----
    const int idx = bx - 2048;
    const int z = idx >> 10;
    const float* src = z == 0 ? wq : z == 1 ? wk : z == 2 ? wv : wo;
    unsigned short* dst = wT + (size_t)z * 1048576;
    const int kb = (idx & 31) * 32, nb = ((idx >> 5) & 31) * 32;
    const int c = tid & 31, r4 = (tid >> 5) * 4;
UNROLL
    for (int i = 0; i < 4; ++i)
      tile[r4 + i][c] = src[(size_t)(kb + r4 + i) * 1024 + nb + c];
    __syncthreads();
UNROLL
    for (int i = 0; i < 4; ++i)
      dst[(size_t)(nb + r4 + i) * 1024 + kb + c] = f2bf(tile[c][r4 + i]);
  } else {
    // ---- rope table (cos,sin) per (t, i<32) ----
    int idx = (bx - 6144) * 256 + tid;
    int t = idx >> 5, i = idx & 31;
    float inv = exp2f(-(float)i * (13.287712379549449f / 32.0f));
    float ang = (float)t * inv;
    ropetab[idx] = make_float2(cosf(ang), sinf(ang));
  }
}

// ======== QKV GEMM: 128x128 tile, BK=64 (16 K-steps), m97 shell, swizzled LDS ========
__global__ __launch_bounds__(256, 3) void gemmqkv(
    const unsigned short* __restrict__ A, const unsigned short* __restrict__ Bt,
    unsigned short* __restrict__ qout, unsigned short* __restrict__ kout,
    unsigned short* __restrict__ vtout, const float2* __restrict__ rope) {
  __shared__ __align__(16) unsigned short As[128 * 64];   // 16KB
  __shared__ __align__(16) unsigned short Bs[128 * 64];   // 16KB
  const int tid = threadIdx.x;
  const int lane = tid & 63, wid = tid >> 6;
  const int wr = wid >> 1, wc = wid & 1;          // wave tile 64x64
  const int g = lane >> 4, r16 = lane & 15;
  const int m0 = blockIdx.y * 128, n0 = blockIdx.x * 128;

  f32x4 acc[4][4];
UNROLL
  for (int i = 0; i < 4; ++i)
UNROLL
    for (int j = 0; j < 4; ++j) acc[i][j] = (f32x4){0.f, 0.f, 0.f, 0.f};

  const int ce = (((tid & 7) ^ ((tid >> 3) & 7)) << 3);
  const unsigned short* gA = A + (size_t)(m0 + (tid >> 3)) * 1024 + ce;
  const unsigned short* gB = Bt + (size_t)(n0 + (tid >> 3)) * 1024 + ce;
  char* lA = (char*)As + tid * 16;
  char* lB = (char*)Bs + tid * 16;

  const int swz = (r16 & 7) << 4;

  for (int u = 0; u < 16; ++u) {
    const int k0 = u * 64;
UNROLL
    for (int s = 0; s < 4; ++s) {
      async16(gA + (size_t)s * 32 * 1024 + k0, lA + s * 4096);
      async16(gB + (size_t)s * 32 * 1024 + k0, lB + s * 4096);
    }
    __syncthreads();
UNROLL
    for (int kk = 0; kk < 2; ++kk) {
      bf16x8 af[4], bfr[4];
UNROLL
      for (int mi = 0; mi < 4; ++mi)
        af[mi] = *(const bf16x8*)((const char*)As +
                  (wr * 64 + mi * 16 + r16) * 128 + ((kk * 64 + g * 16) ^ swz));
UNROLL
      for (int ni = 0; ni < 4; ++ni)
        bfr[ni] = *(const bf16x8*)((const char*)Bs +
                  (wc * 64 + ni * 16 + r16) * 128 + ((kk * 64 + g * 16) ^ swz));
UNROLL
      for (int mi = 0; mi < 4; ++mi)
UNROLL
        for (int ni = 0; ni < 4; ++ni)
          acc[mi][ni] = __builtin_amdgcn_mfma_f32_16x16x32_bf16(af[mi], bfr[ni],
                                                                acc[mi][ni], 0, 0, 0);
    }
    __syncthreads();
  }

  // ---- fused RoPE + scatter epilogue (q/k/vt) ----
  const int which = n0 >> 10;
  const int b = (m0 >= 2048) ? 1 : 0;
  const float QSCL = 0.18033688011112042f;        // 1/sqrt(64) * log2(e)
UNROLL
  for (int mi = 0; mi < 4; ++mi) {
    const int rowb = m0 + wr * 64 + mi * 16 + g * 4;
    const int trow = rowb & 2047;
UNROLL
    for (int ni = 0; ni < 4; ++ni) {
      const int n = n0 + wc * 64 + ni * 16 + r16;
      const int h = (n >> 6) & 15, e = n & 63;
      f32x4 v = acc[mi][ni];
      if (which < 2) {
        const int fi = e >> 1;
        const bool ev = (e & 1) == 0;
UNROLL
        for (int j = 0; j < 4; ++j) {
          float2 cs = rope[(trow + j) * 32 + fi];
          float p = __shfl_xor(v[j], 1);
          v[j] = ev ? (v[j] * cs.x - p * cs.y) : (v[j] * cs.x + p * cs.y);
        }
        if (which == 0) { v[0] *= QSCL; v[1] *= QSCL; v[2] *= QSCL; v[3] *= QSCL; }
      }
      if (which == 2) {
        size_t base = (((size_t)b * 16 + h) * 64 + e) * 2048 + trow;
        ushort4 pkv = {f2bf(v[0]), f2bf(v[1]), f2bf(v[2]), f2bf(v[3])};
        *(ushort4*)(vtout + base) = pkv;
      } else {
        unsigned short* dst = (which == 0) ? qout : kout;
        size_t base = (((size_t)b * 16 + h) * 2048 + trow) * 64 + e;
UNROLL
        for (int j = 0; j < 4; ++j) dst[base + (size_t)j * 64] = f2bf(v[j]);
      }
    }
  }
}

// ======== output projection: 64x64 tiles, BK=64, double-buffered + counted vmcnt ========
__global__ __launch_bounds__(256, 4) void gemm_o(
    const unsigned short* __restrict__ A, const unsigned short* __restrict__ Bt,
    float* __restrict__ out) {
  __shared__ __align__(16) unsigned short As[2][64 * 64]; // 2 x 8KB
  __shared__ __align__(16) unsigned short Bs[2][64 * 64]; // 2 x 8KB
  const int tid = threadIdx.x;
  const int lane = tid & 63, wid = tid >> 6;
  const int wm = wid >> 1, wn = wid & 1;          // wave tile 32x32
  const int g = lane >> 4, r16 = lane & 15;
  const int m0 = blockIdx.y * 64, n0 = blockIdx.x * 64;

  f32x4 acc[2][2];
UNROLL
  for (int i = 0; i < 2; ++i)
UNROLL
    for (int j = 0; j < 2; ++j) acc[i][j] = (f32x4){0.f, 0.f, 0.f, 0.f};

  const int ce = (((tid & 7) ^ ((tid >> 3) & 7)) << 3);
  const unsigned short* gA = A + (size_t)(m0 + (tid >> 3)) * 1024 + ce;
  const unsigned short* gB = Bt + (size_t)(n0 + (tid >> 3)) * 1024 + ce;
  const int dst0 = tid * 16;
  const int swz = (r16 & 7) << 4;

#define OSTG(bb, koff) { \
    async16(gA + (koff),             (char*)As[bb] + dst0); \
    async16(gA + 32 * 1024 + (koff), (char*)As[bb] + dst0 + 4096); \
    async16(gB + (koff),             (char*)Bs[bb] + dst0); \
    async16(gB + 32 * 1024 + (koff), (char*)Bs[bb] + dst0 + 4096); }

  OSTG(0, 0)
  for (int u = 0; u < 16; ++u) {
    const int bsel = u & 1;
    if (u + 1 < 16) { OSTG(bsel ^ 1, (u + 1) * 64) }
    __builtin_amdgcn_sched_barrier(0);
    if (u + 1 < 16) { asm volatile("s_waitcnt vmcnt(4)" ::: "memory"); }
    else            { asm volatile("s_waitcnt vmcnt(0)" ::: "memory"); }
    __builtin_amdgcn_s_barrier();
    __builtin_amdgcn_sched_barrier(0);
UNROLL
    for (int kk = 0; kk < 2; ++kk) {
      bf16x8 af[2], bfr[2];
UNROLL
      for (int mi = 0; mi < 2; ++mi)
        af[mi] = *(const bf16x8*)((const char*)As[bsel] +
                  (wm * 32 + mi * 16 + r16) * 128 + ((kk * 64 + g * 16) ^ swz));
UNROLL
      for (int ni = 0; ni < 2; ++ni)
        bfr[ni] = *(const bf16x8*)((const char*)Bs[bsel] +
                  (wn * 32 + ni * 16 + r16) * 128 + ((kk * 64 + g * 16) ^ swz));
UNROLL
      for (int mi = 0; mi < 2; ++mi)
UNROLL
        for (int ni = 0; ni < 2; ++ni)
          acc[mi][ni] = __builtin_amdgcn_mfma_f32_16x16x32_bf16(af[mi], bfr[ni],
                                                                acc[mi][ni], 0, 0, 0);
    }
    __builtin_amdgcn_sched_barrier(0);
    __builtin_amdgcn_s_barrier();
  }
#undef OSTG

UNROLL
  for (int mi = 0; mi < 2; ++mi) {
    const int rowb = m0 + wm * 32 + mi * 16 + g * 4;
UNROLL
    for (int ni = 0; ni < 2; ++ni) {
      const int n = n0 + wn * 32 + ni * 16 + r16;
UNROLL
      for (int j = 0; j < 4; ++j)
        out[(size_t)(rowb + j) * 1024 + n] = acc[mi][ni][j];
    }
  }
}

// ======== flash attention: scale-free softmax, l via MFMA, PAIRED-tile pipeline ========
// 2 KV-tiles per sync interval; 4x16KB LDS bufs; exactly 8 loads/wave/pair
// (tail-clamped dummies) so vmcnt(8) is exact; last pair drains vmcnt(0).
__device__ const signed char c_qt[32]   = {15,15,10,10,15,14,14,14,13, 9, 9, 4,13,13,12,12, 8, 8,12,11,11,11, 7, 7, 3, 6, 6, 5, 5, 2, 1, 0};
__device__ const signed char c_t0[32]   = { 0,11, 0,11,22, 0,10,20, 0, 0,10, 0,10,19, 0, 9, 0, 9,18, 0, 8,16, 0, 8, 0, 0, 7, 0, 6, 0, 0, 0};
__device__ const signed char c_len[32]  = {11,11,11,11,10,10,10,10,10,10,10,10, 9, 9, 9, 9, 9, 9, 8, 8, 8, 8, 8, 8, 8, 7, 7, 6, 6, 6, 4, 2};
__device__ const signed char c_slot[32] = {24,25,10,11,26,21,22,23,18, 8, 9,-1,19,20,15,16, 6, 7,17,12,13,14, 4, 5,-1, 2, 3, 0, 1,-1,-1,-1};

__global__ __launch_bounds__(256, 2) void attn4(
    const unsigned short* __restrict__ qb, const unsigned short* __restrict__ kb,
    const unsigned short* __restrict__ vtb, unsigned short* __restrict__ attnb,
    unsigned short* __restrict__ po, float* __restrict__ ml) {
  __shared__ __align__(16) char smem[4][16384];   // [buf][K 8KB | V^T 8KB]
  const int tid = threadIdx.x;
  const int lane = tid & 63, w = tid >> 6;
  const int l31 = lane & 31, h = lane >> 5;
  const int bh = blockIdx.x;                      // XCD = bh % 8 (L2 KV locality)
  const int item = blockIdx.y;
  const int qt = c_qt[item];
  const int t0 = c_t0[item];
  const int t1 = t0 + c_len[item];
  const int slot = c_slot[item];
  const int q0w = qt * 128 + w * 32;
  const int qg = q0w + l31;
  const size_t kvbase = (size_t)bh * (2048 * 64);

  bf16x8 qf[4];
  const unsigned short* qp = qb + kvbase + (size_t)qg * 64 + h * 8;
UNROLL
  for (int kk = 0; kk < 4; ++kk) qf[kk] = *(const bf16x8*)(qp + kk * 16);

  u32x4 of; of[0] = of[1] = of[2] = of[3] = 0x3F803F80u;  // 8 x bf16(1.0)
  const bf16x8 onesf = __builtin_bit_cast(bf16x8, of);

  const int lr = lane >> 3;
  const int cb2 = ((lane & 7) ^ lr) << 3;
  const bool isK = (w < 2);
  const int c0 = isK ? w * 4 : (w - 2) * 4;
  const unsigned short* srcp[4];
  int dstoff[4];
  const size_t step = isK ? 4096 : 64;
UNROLL
  for (int s = 0; s < 4; ++s) {
    int r = (c0 + s) * 8 + lr;
    srcp[s] = isK ? (kb + kvbase + (size_t)r * 64 + cb2)
                  : (vtb + kvbase + (size_t)r * 2048 + cb2);
    dstoff[s] = (w * 4 + s) * 1024 + lane * 16;
  }

  f32x16 o0, o1, lacc;
UNROLL
  for (int r = 0; r < 16; ++r) { o0[r] = 0.f; o1[r] = 0.f; lacc[r] = 0.f; }

#define STAGE_T(tv, bufv) { \
    const int tc_ = ((tv) < t1) ? (tv) : (t1 - 1); \
    char* db_ = &smem[(bufv)][0]; \
    async16(srcp[0] + (size_t)tc_ * step, db_ + dstoff[0]); \
    async16(srcp[1] + (size_t)tc_ * step, db_ + dstoff[1]); \
    async16(srcp[2] + (size_t)tc_ * step, db_ + dstoff[2]); \
    async16(srcp[3] + (size_t)tc_ * step, db_ + dstoff[3]); }

  const int np = (t1 - t0 + 1) >> 1;              // pairs
  STAGE_T(t0, 0) STAGE_T(t0 + 1, 1)
  if (np > 1) { STAGE_T(t0 + 2, 2) STAGE_T(t0 + 3, 3) }

  const int swz = (l31 & 7) << 4;
  for (int p = 0; p < np; ++p) {
    const int tp = t0 + 2 * p;
    __builtin_amdgcn_sched_barrier(0);
    if (p + 1 < np) { asm volatile("s_waitcnt vmcnt(8)" ::: "memory"); }
    else            { asm volatile("s_waitcnt vmcnt(0)" ::: "memory"); }
    __builtin_amdgcn_s_barrier();
    __builtin_amdgcn_sched_barrier(0);
UNROLL
    for (int sub = 0; sub < 2; ++sub) {
      const int t = tp + sub;
      const int kt0 = t << 6;
      if (t < t1 && kt0 <= q0w + 31) {
        const char* cbuf = &smem[(2 * p + sub) & 3][0];
        f32x16 sa, sb;
UNROLL
        for (int r = 0; r < 16; ++r) { sa[r] = 0.f; sb[r] = 0.f; }
        __builtin_amdgcn_s_setprio(1);
UNROLL
        for (int kk = 0; kk < 4; ++kk) {
          bf16x8 kf = *(const bf16x8*)(cbuf + l31 * 128 + ((kk * 32 + h * 16) ^ swz));
          sa = __builtin_amdgcn_mfma_f32_32x32x16_bf16(kf, qf[kk], sa, 0, 0, 0);
        }
UNROLL
        for (int kk = 0; kk < 4; ++kk) {
          bf16x8 kf = *(const bf16x8*)(cbuf + (32 + l31) * 128 + ((kk * 32 + h * 16) ^ swz));
          sb = __builtin_amdgcn_mfma_f32_32x32x16_bf16(kf, qf[kk], sb, 0, 0, 0);
        }
        __builtin_amdgcn_s_setprio(0);
        if (kt0 + 63 > q0w) {                     // causal mask (diagonal only)
UNROLL
          for (int r = 0; r < 16; ++r) {
            int koff = (r & 3) + 8 * (r >> 2) + 4 * h;
            if (kt0 + koff > qg) sa[r] = -3e38f;
            if (kt0 + 32 + koff > qg) sb[r] = -3e38f;
          }
        }
UNROLL
        for (int r = 0; r < 16; ++r) {
          sa[r] = exp2f(sa[r]);
          sb[r] = exp2f(sb[r]);
        }
        unsigned int lo[8], hi[8];
UNROLL
        for (int b8 = 0; b8 < 4; ++b8) {
          lo[b8]     = cvtpk(sa[4 * b8], sa[4 * b8 + 1]);
          hi[b8]     = cvtpk(sa[4 * b8 + 2], sa[4 * b8 + 3]);
          lo[4 + b8] = cvtpk(sb[4 * b8], sb[4 * b8 + 1]);
          hi[4 + b8] = cvtpk(sb[4 * b8 + 2], sb[4 * b8 + 3]);
        }
        bf16x8 pa[4];
UNROLL
        for (int j = 0; j < 4; ++j) {
          const int bb = (j >> 1) * 4 + (j & 1) * 2;
          unsigned int a0 = lo[bb], b0 = lo[bb + 1];
          unsigned int a1 = hi[bb], b1 = hi[bb + 1];
          asm volatile("v_permlane32_swap_b32 %0, %1" : "+v"(a0), "+v"(b0));
          asm volatile("v_permlane32_swap_b32 %0, %1" : "+v"(a1), "+v"(b1));
          u32x4 f;
          f[0] = a0; f[1] = a1; f[2] = b0; f[3] = b1;
          pa[j] = __builtin_bit_cast(bf16x8, f);
        }
        __builtin_amdgcn_s_setprio(1);
UNROLL
        for (int j = 0; j < 4; ++j) {
          bf16x8 v0 = *(const bf16x8*)(cbuf + 8192 + l31 * 128 + ((j * 32 + h * 16) ^ swz));
          bf16x8 v1 = *(const bf16x8*)(cbuf + 8192 + (32 + l31) * 128 + ((j * 32 + h * 16) ^ swz));
          o0 = __builtin_amdgcn_mfma_f32_32x32x16_bf16(pa[j], v0, o0, 0, 0, 0);
          o1 = __builtin_amdgcn_mfma_f32_32x32x16_bf16(pa[j], v1, o1, 0, 0, 0);
          lacc = __builtin_amdgcn_mfma_f32_32x32x16_bf16(pa[j], onesf, lacc, 0, 0, 0);
        }
        __builtin_amdgcn_s_setprio(0);
      }
    }
    __builtin_amdgcn_sched_barrier(0);
    __builtin_amdgcn_s_barrier();
    if (p + 2 < np) { STAGE_T(tp + 4, (2 * p) & 3) STAGE_T(tp + 5, (2 * p + 1) & 3) }
  }
#undef STAGE_T

  // ---- epilogue: lacc[r] is l for this lane's rows ----
  if (slot < 0) {
    const int b = bh >> 4, hh = bh & 15;
UNROLL
    for (int r = 0; r < 16; ++r) {
      const int qg2 = q0w + (r & 3) + 8 * (r >> 2) + 4 * h;
      const size_t base = (((size_t)b * 2048 + qg2) * 16 + hh) * 64 + l31;
      const float iv = 1.0f / lacc[r];
      attnb[base]      = f2bf(o0[r] * iv);
      attnb[base + 32] = f2bf(o1[r] * iv);
    }
  } else {
    const int p = bh * 27 + slot;
    if (l31 == 0) {
UNROLL
      for (int r = 0; r < 16; ++r)
        ml[p * 128 + w * 32 + (r & 3) + 8 * (r >> 2) + 4 * h] = lacc[r];
    }
    unsigned short* pb = po + (size_t)p * 8192;
UNROLL
    for (int r = 0; r < 16; ++r) {
      const int rl = w * 32 + (r & 3) + 8 * (r >> 2) + 4 * h;
      const float iv = 1.0f / lacc[r];
      pb[rl * 64 + l31]      = f2bf(o0[r] * iv);
      pb[rl * 64 + l31 + 32] = f2bf(o1[r] * iv);
    }
  }
}

// ---------------- combine partials: l-weighted average (no exp) ----------------
__global__ void attn_combine(const unsigned short* __restrict__ po,
                             const float* __restrict__ ml,
                             unsigned short* __restrict__ attnb) {
  const int idx = blockIdx.x * 256 + threadIdx.x;   // 32*11*128*4 = 180224
  const int cg = idx & 3;                           // 16 cols each
  const int row = (idx >> 2) & 127;
  const int t2 = idx >> 9;                          // bh*11 + qi
  const int qi = t2 % 11;
  const int bh = t2 / 11;
  const int qt = qi + 5;
  const int cnt = (qt < 11) ? 2 : 3;
  const int base = (qt < 11) ? (qt - 5) * 2 : 12 + (qt - 11) * 3;
  const int slotg = bh * 27 + base;
  float acc[16];
UNROLL
  for (int i = 0; i < 16; ++i) acc[i] = 0.f;
  float wsum = 0.f;
  for (int i = 0; i < cnt; ++i) {
    const float l = ml[(slotg + i) * 128 + row];
    wsum += l;
    const ushort4* p = (const ushort4*)(po + (size_t)(slotg + i) * 8192 + row * 64 + cg * 16);
UNROLL
    for (int v = 0; v < 4; ++v) {
      ushort4 u = p[v];
      acc[v * 4 + 0] += l * bf2f(u.x);
      acc[v * 4 + 1] += l * bf2f(u.y);
      acc[v * 4 + 2] += l * bf2f(u.z);
      acc[v * 4 + 3] += l * bf2f(u.w);
    }
  }
  const float inv = 1.0f / wsum;
  const int b = bh >> 4, hh = bh & 15;
  const int q = qt * 128 + row;
  ushort4* out = (ushort4*)(attnb + (((size_t)b * 2048 + q) * 16 + hh) * 64 + cg * 16);
UNROLL
  for (int v = 0; v < 4; ++v) {
    ushort4 o;
    o.x = f2bf(acc[v * 4 + 0] * inv);
    o.y = f2bf(acc[v * 4 + 1] * inv);
    o.z = f2bf(acc[v * 4 + 2] * inv);
    o.w = f2bf(acc[v * 4 + 3] * inv);
    out[v] = o;
  }
}

extern "C" void kernel_launch(void* const* d_in, const int* in_sizes, int n_in,
                              void* d_out, int out_size, void* d_ws, size_t ws_size,
                              hipStream_t stream) {
  (void)in_sizes; (void)n_in; (void)out_size; (void)ws_size;
  const float* x = (const float*)d_in[0];
  const float* wq = (const float*)d_in[2];
  const float* wk = (const float*)d_in[3];
  const float* wv = (const float*)d_in[4];
  const float* wo = (const float*)d_in[5];

  unsigned short* xb = (unsigned short*)d_ws;           // 4M elems (8MB)
  unsigned short* wT = xb + 4 * 1024 * 1024;            // 4M
  float2* rope = (float2*)(wT + 4 * 1024 * 1024);       // 64K float2 (512KB)
  unsigned short* qb = (unsigned short*)(rope + 65536); // 4M
  unsigned short* kbuf = qb + 4 * 1024 * 1024;          // 4M
  unsigned short* vtb = kbuf + 4 * 1024 * 1024;         // 4M
  unsigned short* attnb = vtb + 4 * 1024 * 1024;        // 4M

  unsigned short* po = xb;          // partials alias xb+weights (dead after gemmqkv)
  float* mlb = (float*)rope;        // l-table aliases rope (dead after gemmqkv)

  prep_all<<<dim3(6400), dim3(256), 0, stream>>>(x, wq, wk, wv, wo, xb, wT, rope);
  gemmqkv<<<dim3(24, 32), dim3(256), 0, stream>>>(xb, wT, qb, kbuf, vtb, rope);
  attn4<<<dim3(32, 32), dim3(256), 0, stream>>>(qb, kbuf, vtb, attnb, po, mlb);
  attn_combine<<<dim3(704), dim3(256), 0, stream>>>(po, mlb, attnb);
  gemm_o<<<dim3(16, 64), dim3(256), 0, stream>>>(attnb, wT + 3 * 1024 * 1024,
                                                 (float*)d_out);
}